// Round 18
// baseline (566.902 us; speedup 1.0000x reference)
//
#include <hip/hip_runtime.h>
#include <hip/hip_fp16.h>
#include <math.h>

// Problem constants: B=8, Tt=16, C=1, H=W=512, 4 in-channels, 10 T-planes.
#define Bd 8
#define Td 16
#define Hd 512
#define Wd 512
#define HWc (Hd * Wd)          // 262144
#define NPIX (Bd * HWc)        // 2,097,152

// ---------------- conv tiling: 16x16 tile, 1 px/thread, 256 threads ----------
#define CT  16
#define CR  18
#define CP  20
#define CTH2 256

// ---------------- wide fused kernel (fallback): 128x64 core, halo 6 ----------
#define WCR 128
#define WCC 64
#define WH  6
#define WTR 140
#define WTC 76
#define WLP 77
#define WTHR 1024
#define WRPG 11
#define WNG 13

// ---------------- lane-column fused kernel (KR=6, spill-proof) ---------------
#define KCR 64                 // core rows
#define KCC 52                 // core cols
#define KH  6                  // halo
#define KTR 76                 // region rows
#define KTC 64                 // region cols == lanes of one wave
#define KG  13                 // waves (row groups) per block
#define KR  6                  // owned rows per thread (13*6=78 >= 74 interior)
#define KTHR (KG * 64)         // 832 threads

// v_fma_mix_f32: acc(f32) += w(f32) * h.lo/h.hi(f16) in ONE instruction.
#define FMAMIX_LO(acc, wv, hv) \
    asm("v_fma_mix_f32 %0, %1, %2, %0 op_sel:[0,0,0] op_sel_hi:[0,1,0]" \
        : "+v"(acc) : "v"(wv), "v"(hv))
#define FMAMIX_HI(acc, wv, hv) \
    asm("v_fma_mix_f32 %0, %1, %2, %0 op_sel:[0,1,0] op_sel_hi:[0,1,0]" \
        : "+v"(acc) : "v"(wv), "v"(hv))

__device__ __forceinline__ float hi_half_f32(unsigned h) {
    __half2 hh = *(__half2*)&h;
    return __half2float(__high2half(hh));
}

// Whole-wave lane shifts (verified r14): left = lane-1, right = lane+1.
__device__ __forceinline__ float lane_left(float v) {
#if __has_builtin(__builtin_amdgcn_mov_dpp)
    return __int_as_float(__builtin_amdgcn_mov_dpp(__float_as_int(v),
                                                   0x138, 0xf, 0xf, true));
#else
    return __shfl_up(v, 1);
#endif
}
__device__ __forceinline__ float lane_right(float v) {
#if __has_builtin(__builtin_amdgcn_mov_dpp)
    return __int_as_float(__builtin_amdgcn_mov_dpp(__float_as_int(v),
                                                   0x130, 0xf, 0xf, true));
#else
    return __shfl_down(v, 1);
#endif
}

// ---------------------------------------------------------------------------
// Kernel 1 (r17 proven): o-outer conv, 1 px/thread, contiguous weight loads.
// T = conv2d(x[:,-4:,0],W)+b fused with xt0 -> out[:,0].
// T stored as half2 pairs: plane q holds (T[2q], T[2q+1]); layout (B,5,H,W).
// ---------------------------------------------------------------------------
__global__ __launch_bounds__(CTH2)
void conv_step0_kernel(const float* __restrict__ x,
                       const float* __restrict__ Wu,
                       const float* __restrict__ bu,
                       __half2* __restrict__ T,
                       float* __restrict__ out) {
    __shared__ float sX[4][CR][CP];     // 5.76 KB

    int bx  = blockIdx.x;               // 8192 = 8 b * 32 * 32 tiles
    int b   = bx >> 10;
    int rem = bx & 1023;
    int by  = rem >> 5;
    int bc  = rem & 31;
    int i0  = by * CT;
    int j0  = bc * CT;

    const float* xb = x + ((size_t)b * Td + 12) * HWc;
    int tid = threadIdx.x;

    for (int idx = tid; idx < 4 * CR * CR; idx += CTH2) {
        int ch = idx / (CR * CR);
        int r2 = idx - ch * (CR * CR);
        int r  = r2 / CR;
        int c  = r2 - r * CR;
        int gi = i0 + r - 1, gj = j0 + c - 1;
        float v = 0.0f;
        if ((unsigned)gi < (unsigned)Hd && (unsigned)gj < (unsigned)Wd)
            v = xb[(size_t)ch * HWc + gi * Wd + gj];
        sX[ch][r][c] = v;
    }
    __syncthreads();

    int tx = tid & 15;
    int ty = tid >> 4;

    float xf[36];
    #pragma unroll
    for (int ch = 0; ch < 4; ++ch)
        #pragma unroll
        for (int kh = 0; kh < 3; ++kh)
            #pragma unroll
            for (int kw = 0; kw < 3; ++kw)
                xf[(ch * 3 + kh) * 3 + kw] = sX[ch][ty + kh][tx + kw];

    int gi = i0 + ty;
    int gj = j0 + tx;
    size_t pix = (size_t)gi * Wd + gj;
    __half2* Tb = T + (size_t)b * 5 * HWc;

    float o0 = 0.0f;
    float accPrev = 0.0f;
    #pragma unroll
    for (int o = 0; o < 10; ++o) {
        const float* wo = Wu + o * 36;
        float acc = bu[o];
        #pragma unroll
        for (int z = 0; z < 36; ++z)
            acc += xf[z] * wo[z];

        if (o < 9)
            o0 += xf[(3 * 3 + (o % 3)) * 3 + (o / 3)] * acc;
        else
            o0 += acc;

        if (o & 1) {
            __half2 h = __floats2half2_rn(accPrev, acc);
            *(unsigned*)(Tb + (size_t)(o >> 1) * HWc + pix) = *(unsigned*)&h;
        }
        accPrev = acc;
    }

    out[(size_t)b * Td * HWc + pix] = o0;
}

// ---------------------------------------------------------------------------
// Kernel 2a (preferred): lane-column fused kernel, KR=6 (spill-proof: treg 30
// + xw 8 + misc ~= 55 VGPR). Wave g owns region rows rs..rs+5 (rs=1+6g),
// lane = region col. Horizontal neighbors via DPP; vertical in-register;
// 2 boundary rows cross LDS per step (double-buffered, 1 barrier/step).
// Ring rows/cols never updated (keep staged x_{t-1}); tail rows (>74) are
// computed but update-masked (r14's verified pattern). Out-of-image pixels
// forced 0 every step. 640 blocks = 8 b * 8 row-tiles * 10 col-tiles.
// ---------------------------------------------------------------------------
__global__ __launch_bounds__(KTHR, 2)
void fused6_lane_kernel(const float* __restrict__ xin,   // out slot t-1 base
                        const __half2* __restrict__ T,
                        float* __restrict__ xout) {      // out slot t base
    __shared__ float bndF[2][KG][64];
    __shared__ float bndL[2][KG][64];

    int tile = blockIdx.x;              // 640
    int b   = tile / 80;
    int rem = tile - b * 80;
    int tr  = rem / 10;
    int tc  = rem - tr * 10;
    int ri  = tr * KCR - KH;
    int rj  = tc * KCC - KH;

    int tid  = threadIdx.x;
    int g    = tid >> 6;                // wave-uniform group 0..12
    int lane = tid & 63;

    int  gj     = rj + lane;
    bool colin  = (unsigned)gj < (unsigned)Wd;
    bool lanein = (lane >= 1) && (lane <= KTC - 2);
    int  gjc    = min(max(gj, 0), Wd - 1);

    int rs = 1 + g * KR;                // first owned region row (1..73)

    const float* xb = xin + (size_t)b * Td * HWc;
    const __half2* Tb = T + (size_t)b * 5 * HWc;

    // Initial column state: rows rs-1 .. rs+6 (8 values), zero outside image
    // or beyond the region (clamped addresses feed only masked outputs).
    float xw[KR + 2];
    #pragma unroll
    for (int k = 0; k < KR + 2; ++k) {
        int row = rs - 1 + k;
        int gi  = ri + row;
        bool in = ((unsigned)gi < (unsigned)Hd) && colin && (row <= KTR - 1);
        int gic = min(max(gi, 0), Hd - 1);
        float v = xb[gic * Wd + gjc];
        xw[k] = in ? v : 0.0f;
    }

    // T coefs (raw uints; clamped addresses feed only masked outputs).
    unsigned treg[KR][5];
    #pragma unroll
    for (int j = 0; j < KR; ++j) {
        int gi  = ri + rs + j;
        int gic = min(max(gi, 0), Hd - 1);
        const unsigned* tp = (const unsigned*)(Tb + gic * Wd + gjc);
        #pragma unroll
        for (int q = 0; q < 5; ++q)
            treg[j][q] = tp[(size_t)q * HWc];
    }

    int p = 0;
    #pragma unroll
    for (int s = 1; s <= 6; ++s) {
        float pC = xw[0], pL = lane_left(pC), pR = lane_right(pC);
        float cC = xw[1], cL = lane_left(cC), cR = lane_right(cC);
        #pragma unroll
        for (int j = 1; j <= KR; ++j) {
            float nC = xw[j + 1];
            float nL = lane_left(nC);
            float nR = lane_right(nC);
            unsigned h0 = treg[j - 1][0], h1 = treg[j - 1][1],
                     h2 = treg[j - 1][2], h3 = treg[j - 1][3],
                     h4 = treg[j - 1][4];
            // k = dj*3+di multiplies x[r+di-1][c+dj-1]
            float a = hi_half_f32(h4);          // T9
            FMAMIX_LO(a, pL, h0);               // k0: T0
            FMAMIX_HI(a, cL, h0);               // k1: T1
            FMAMIX_LO(a, nL, h1);               // k2: T2
            FMAMIX_HI(a, pC, h1);               // k3: T3
            FMAMIX_LO(a, cC, h2);               // k4: T4
            FMAMIX_HI(a, nC, h2);               // k5: T5
            FMAMIX_LO(a, pR, h3);               // k6: T6
            FMAMIX_HI(a, cR, h3);               // k7: T7
            FMAMIX_LO(a, nR, h4);               // k8: T8
            if ((s & 1) == 0) a = 1.0f / (1.0f + __expf(-a));

            int row = rs + j - 1;
            int gi  = ri + row;
            bool okpix = ((unsigned)gi < (unsigned)Hd) && colin;
            bool upd   = (row <= KTR - 2) && lanein;
            float val  = okpix ? a : 0.0f;
            xw[j] = upd ? val : xw[j];

            pL = cL; pC = cC; pR = cR;
            cL = nL; cC = nC; cR = nR;
        }
        // Exchange group-boundary rows (double-buffered, 1 barrier/step).
        bndF[p][g][lane] = xw[1];
        bndL[p][g][lane] = xw[KR];
        __syncthreads();
        if (g > 0)      xw[0]      = bndL[p][g - 1][lane];
        if (g < KG - 1) xw[KR + 1] = bndF[p][g + 1][lane];
        p ^= 1;
    }

    // Store core rows (region rows 6..69) x cols (6..57), masked to image.
    float* ob = xout + (size_t)b * Td * HWc;
    bool storec = (lane >= KH) && (lane <= KTC - 1 - KH) && colin;
    #pragma unroll
    for (int j = 1; j <= KR; ++j) {
        int row = rs + j - 1;
        if (row >= KH && row <= KTR - 1 - KH) {     // wave-uniform
            int gi = ri + row;                      // in [0,511] when stored
            if (storec) ob[gi * Wd + gj] = xw[j];
        }
    }
}

// ---------------------------------------------------------------------------
// Kernel 2b (fallback, r16 proven): wide LDS ping-pong kernel + fma_mix.
// ---------------------------------------------------------------------------
__global__ __launch_bounds__(WTHR, 2)
void fused6_wide_kernel(const float* __restrict__ xin,
                        const __half2* __restrict__ T,
                        float* __restrict__ xout) {
    __shared__ float sA[WTR * WLP];
    __shared__ float sB[WTR * WLP];

    int tile = blockIdx.x;          // 256
    int b  = tile >> 5;
    int tr = (tile >> 3) & 3;
    int tc = tile & 7;
    int ri = tr * WCR - WH;
    int rj = tc * WCC - WH;

    const float* xb = xin + (size_t)b * Td * HWc;
    const __half2* Tb = T + (size_t)b * 5 * HWc;
    int tid = threadIdx.x;

    for (int idx = tid; idx < WTR * WTC; idx += WTHR) {
        int r = idx / WTC, c = idx - r * WTC;
        int gi = ri + r, gj = rj + c;
        float v = 0.0f;
        if ((unsigned)gi < (unsigned)Hd && (unsigned)gj < (unsigned)Wd)
            v = xb[gi * Wd + gj];
        sA[r * WLP + c] = v;
    }
    for (int idx = tid; idx < 2 * WTC; idx += WTHR) {
        int r = (idx < WTC) ? 0 : (WTR - 1);
        int c = (idx < WTC) ? idx : idx - WTC;
        sB[r * WLP + c] = 0.0f;
    }
    for (int idx = tid; idx < 2 * WTR; idx += WTHR) {
        int r = (idx < WTR) ? idx : idx - WTR;
        int c = (idx < WTR) ? 0 : (WTC - 1);
        sB[r * WLP + c] = 0.0f;
    }

    int g  = tid / WTC;
    int c  = tid - g * WTC;
    int rs = 1 + g * WRPG;
    bool colint = (c >= 1) && (c <= WTC - 2);
    bool active = (g < WNG) && colint;
    int  gj     = rj + c;
    bool colin  = (unsigned)gj < (unsigned)Wd;

    unsigned treg[WRPG][5];
    #pragma unroll
    for (int jj = 0; jj < WRPG; ++jj) {
        int r  = rs + jj;
        int gi = ri + r;
        bool ok = active && (r <= WTR - 2) && ((unsigned)gi < (unsigned)Hd) && colin;
        #pragma unroll
        for (int q = 0; q < 5; ++q) {
            unsigned v = 0u;
            if (ok) v = *(const unsigned*)(Tb + (size_t)q * HWc + gi * Wd + gj);
            treg[jj][q] = v;
        }
    }
    __syncthreads();

    float* cur = sA;
    float* nxt = sB;

    #pragma unroll
    for (int s = 1; s <= 6; ++s) {
        if (active) {
            float w00 = cur[(rs - 1) * WLP + c - 1];
            float w01 = cur[(rs - 1) * WLP + c];
            float w02 = cur[(rs - 1) * WLP + c + 1];
            float w10 = cur[rs * WLP + c - 1];
            float w11 = cur[rs * WLP + c];
            float w12 = cur[rs * WLP + c + 1];
            #pragma unroll
            for (int jj = 0; jj < WRPG; ++jj) {
                int r  = rs + jj;
                int r2 = (r + 1 <= WTR - 1) ? (r + 1) : (WTR - 1);
                float w20 = cur[r2 * WLP + c - 1];
                float w21 = cur[r2 * WLP + c];
                float w22 = cur[r2 * WLP + c + 1];

                unsigned h0 = treg[jj][0], h1 = treg[jj][1], h2 = treg[jj][2],
                         h3 = treg[jj][3], h4 = treg[jj][4];
                float a = hi_half_f32(h4);      // T9
                FMAMIX_LO(a, w00, h0);
                FMAMIX_HI(a, w10, h0);
                FMAMIX_LO(a, w20, h1);
                FMAMIX_HI(a, w01, h1);
                FMAMIX_LO(a, w11, h2);
                FMAMIX_HI(a, w21, h2);
                FMAMIX_LO(a, w02, h3);
                FMAMIX_HI(a, w12, h3);
                FMAMIX_LO(a, w22, h4);
                if ((s & 1) == 0) a = 1.0f / (1.0f + __expf(-a));

                int gi = ri + r;
                bool rowok = (r <= WTR - 2);
                bool inimg = ((unsigned)gi < (unsigned)Hd) && colin;
                if (rowok) nxt[r * WLP + c] = inimg ? a : 0.0f;

                w00 = w10; w01 = w11; w02 = w12;
                w10 = w20; w11 = w21; w12 = w22;
            }
        }
        __syncthreads();
        float* tmp = cur; cur = nxt; nxt = tmp;
    }

    float* ob = xout + (size_t)b * Td * HWc;
    for (int idx = tid; idx < WCR * WCC; idx += WTHR) {
        int rr = idx >> 6, cc = idx & 63;
        ob[(ri + WH + rr) * Wd + (rj + WH + cc)] = cur[(WH + rr) * WLP + (WH + cc)];
    }
}

// ---------------------------------------------------------------------------
// Workspace: T only (B*5*H*W half2 = 40 MB).
// ---------------------------------------------------------------------------
extern "C" void kernel_launch(void* const* d_in, const int* in_sizes, int n_in,
                              void* d_out, int out_size, void* d_ws, size_t ws_size,
                              hipStream_t stream) {
    const float* x  = (const float*)d_in[0];
    const float* Wu = (const float*)d_in[1];
    const float* bu = (const float*)d_in[2];
    float* out = (float*)d_out;
    __half2* T = (__half2*)d_ws;

    conv_step0_kernel<<<8192, CTH2, 0, stream>>>(x, Wu, bu, T, out);

    // Deterministic spill gate: lane kernel only if no scratch.
    hipFuncAttributes attr;
    hipError_t qe = hipFuncGetAttributes(&attr, (const void*)fused6_lane_kernel);
    bool useLane = (qe == hipSuccess) && (attr.localSizeBytes == 0);

    if (useLane) {
        for (int t = 1; t < Td; ++t)
            fused6_lane_kernel<<<640, KTHR, 0, stream>>>(
                out + (size_t)(t - 1) * HWc, T, out + (size_t)t * HWc);
    } else {
        for (int t = 1; t < Td; ++t)
            fused6_wide_kernel<<<256, WTHR, 0, stream>>>(
                out + (size_t)(t - 1) * HWc, T, out + (size_t)t * HWc);
    }
}

// Round 19
// 484.028 us; speedup vs baseline: 1.1712x; 1.1712x over previous
//
#include <hip/hip_runtime.h>
#include <hip/hip_fp16.h>
#include <math.h>

// Problem constants: B=8, Tt=16, C=1, H=W=512, 4 in-channels, 10 T-planes.
#define Bd 8
#define Td 16
#define Hd 512
#define Wd 512
#define HWc (Hd * Wd)          // 262144
#define NPIX (Bd * HWc)        // 2,097,152

// ---------------- conv tiling: 16x16 tile, 1 px/thread, 256 threads ----------
#define CT  16
#define CR  18
#define CP  20
#define CTH2 256

// ---------------- wide fused kernel: 128x64 core, halo 6 ---------------------
#define WCR 128
#define WCC 64
#define WH  6
#define WTR 140
#define WTC 76
#define WLP 77
#define WTHR 1024
#define WRPG 11
#define WNG 13

// v_fma_mix_f32: acc(f32) += w(f32) * h.lo/h.hi(f16) in ONE instruction.
#define FMAMIX_LO(acc, wv, hv) \
    asm("v_fma_mix_f32 %0, %1, %2, %0 op_sel:[0,0,0] op_sel_hi:[0,1,0]" \
        : "+v"(acc) : "v"(wv), "v"(hv))
#define FMAMIX_HI(acc, wv, hv) \
    asm("v_fma_mix_f32 %0, %1, %2, %0 op_sel:[0,1,0] op_sel_hi:[0,1,0]" \
        : "+v"(acc) : "v"(wv), "v"(hv))

__device__ __forceinline__ float hi_half_f32(unsigned h) {
    __half2 hh = *(__half2*)&h;
    return __half2float(__high2half(hh));
}

// ---------------------------------------------------------------------------
// Kernel 1 (r17 proven): o-outer conv, 1 px/thread, contiguous weight loads.
// T = conv2d(x[:,-4:,0],W)+b fused with xt0 -> out[:,0].
// T stored as half2 pairs: plane q holds (T[2q], T[2q+1]); layout (B,5,H,W).
// ---------------------------------------------------------------------------
__global__ __launch_bounds__(CTH2)
void conv_step0_kernel(const float* __restrict__ x,
                       const float* __restrict__ Wu,
                       const float* __restrict__ bu,
                       __half2* __restrict__ T,
                       float* __restrict__ out) {
    __shared__ float sX[4][CR][CP];     // 5.76 KB

    int bx  = blockIdx.x;               // 8192 = 8 b * 32 * 32 tiles
    int b   = bx >> 10;
    int rem = bx & 1023;
    int by  = rem >> 5;
    int bc  = rem & 31;
    int i0  = by * CT;
    int j0  = bc * CT;

    const float* xb = x + ((size_t)b * Td + 12) * HWc;
    int tid = threadIdx.x;

    for (int idx = tid; idx < 4 * CR * CR; idx += CTH2) {
        int ch = idx / (CR * CR);
        int r2 = idx - ch * (CR * CR);
        int r  = r2 / CR;
        int c  = r2 - r * CR;
        int gi = i0 + r - 1, gj = j0 + c - 1;
        float v = 0.0f;
        if ((unsigned)gi < (unsigned)Hd && (unsigned)gj < (unsigned)Wd)
            v = xb[(size_t)ch * HWc + gi * Wd + gj];
        sX[ch][r][c] = v;
    }
    __syncthreads();

    int tx = tid & 15;
    int ty = tid >> 4;

    float xf[36];
    #pragma unroll
    for (int ch = 0; ch < 4; ++ch)
        #pragma unroll
        for (int kh = 0; kh < 3; ++kh)
            #pragma unroll
            for (int kw = 0; kw < 3; ++kw)
                xf[(ch * 3 + kh) * 3 + kw] = sX[ch][ty + kh][tx + kw];

    int gi = i0 + ty;
    int gj = j0 + tx;
    size_t pix = (size_t)gi * Wd + gj;
    __half2* Tb = T + (size_t)b * 5 * HWc;

    float o0 = 0.0f;
    float accPrev = 0.0f;
    #pragma unroll
    for (int o = 0; o < 10; ++o) {
        const float* wo = Wu + o * 36;  // 36 contiguous weights -> batched s_load
        float acc = bu[o];
        #pragma unroll
        for (int z = 0; z < 36; ++z)
            acc += xf[z] * wo[z];

        // step0 inline: k = dj*3+di multiplies x15[i+di-1, j+dj-1].
        if (o < 9)
            o0 += xf[(3 * 3 + (o % 3)) * 3 + (o / 3)] * acc;
        else
            o0 += acc;

        if (o & 1) {
            __half2 h = __floats2half2_rn(accPrev, acc);
            *(unsigned*)(Tb + (size_t)(o >> 1) * HWc + pix) = *(unsigned*)&h;
        }
        accPrev = acc;
    }

    out[(size_t)b * Td * HWc + pix] = o0;
}

// ---------------------------------------------------------------------------
// Kernel 2: one scan-body iteration = 6 fused stencil steps, 128x64 core
// (region 140x76), 256 blocks = 1 block/CU, one round. Thread owns column
// c = t%76, rows rs..rs+10; 55 half2 T coefs in VGPRs (fma_mix taps); x
// ping-pongs in LDS. Sigmoid at even sub-steps. Ring never written;
// contamination <=1 px/step; halo 6 protects the core.
// CHANGE vs r15/r16: step 6 stores the core DIRECTLY to global from
// registers (s is compile-time) -- removes the step-6 LDS write, the final
// barrier, and the LDS->global copy loop. Buffer parity: after 5 swaps
// cur = step-5 state; step 6 reads it and stores. Core px always in-image.
// ---------------------------------------------------------------------------
__global__ __launch_bounds__(WTHR, 2)
void fused6_wide_kernel(const float* __restrict__ xin,   // out slot t-1 base
                        const __half2* __restrict__ T,
                        float* __restrict__ xout) {      // out slot t base
    __shared__ float sA[WTR * WLP];
    __shared__ float sB[WTR * WLP];

    int tile = blockIdx.x;          // 256 = 8 b * 4 tr * 8 tc
    int b  = tile >> 5;
    int tr = (tile >> 3) & 3;
    int tc = tile & 7;
    int ri = tr * WCR - WH;
    int rj = tc * WCC - WH;

    const float* xb = xin + (size_t)b * Td * HWc;
    const __half2* Tb = T + (size_t)b * 5 * HWc;
    float* ob = xout + (size_t)b * Td * HWc;
    int tid = threadIdx.x;

    // Stage sA (zeros outside image).
    for (int idx = tid; idx < WTR * WTC; idx += WTHR) {
        int r = idx / WTC, c = idx - r * WTC;
        int gi = ri + r, gj = rj + c;
        float v = 0.0f;
        if ((unsigned)gi < (unsigned)Hd && (unsigned)gj < (unsigned)Wd)
            v = xb[gi * Wd + gj];
        sA[r * WLP + c] = v;
    }
    // Zero only sB's ring (never written by the step loop; interior fully
    // rewritten each step before being read).
    for (int idx = tid; idx < 2 * WTC; idx += WTHR) {
        int r = (idx < WTC) ? 0 : (WTR - 1);
        int c = (idx < WTC) ? idx : idx - WTC;
        sB[r * WLP + c] = 0.0f;
    }
    for (int idx = tid; idx < 2 * WTR; idx += WTHR) {
        int r = (idx < WTR) ? idx : idx - WTR;
        int c = (idx < WTR) ? 0 : (WTC - 1);
        sB[r * WLP + c] = 0.0f;
    }

    int g  = tid / WTC;             // row group 0..12 valid
    int c  = tid - g * WTC;         // column 0..75
    int rs = 1 + g * WRPG;          // first owned row
    bool colint = (c >= 1) && (c <= WTC - 2);
    bool active = (g < WNG) && colint;
    int  gj     = rj + c;
    bool colin  = (unsigned)gj < (unsigned)Wd;
    bool colcore = (c >= WH) && (c <= WTC - 1 - WH);   // core column

    // T coefficients: 5 half2 (raw u32) per owned row.
    unsigned treg[WRPG][5];
    #pragma unroll
    for (int jj = 0; jj < WRPG; ++jj) {
        int r  = rs + jj;
        int gi = ri + r;
        bool ok = active && (r <= WTR - 2) && ((unsigned)gi < (unsigned)Hd) && colin;
        #pragma unroll
        for (int q = 0; q < 5; ++q) {
            unsigned v = 0u;
            if (ok) v = *(const unsigned*)(Tb + (size_t)q * HWc + gi * Wd + gj);
            treg[jj][q] = v;
        }
    }
    __syncthreads();

    float* cur = sA;
    float* nxt = sB;

    #pragma unroll
    for (int s = 1; s <= 6; ++s) {
        if (active) {
            float w00 = cur[(rs - 1) * WLP + c - 1];
            float w01 = cur[(rs - 1) * WLP + c];
            float w02 = cur[(rs - 1) * WLP + c + 1];
            float w10 = cur[rs * WLP + c - 1];
            float w11 = cur[rs * WLP + c];
            float w12 = cur[rs * WLP + c + 1];
            #pragma unroll
            for (int jj = 0; jj < WRPG; ++jj) {
                int r  = rs + jj;
                int r2 = (r + 1 <= WTR - 1) ? (r + 1) : (WTR - 1);
                float w20 = cur[r2 * WLP + c - 1];
                float w21 = cur[r2 * WLP + c];
                float w22 = cur[r2 * WLP + c + 1];

                unsigned h0 = treg[jj][0], h1 = treg[jj][1], h2 = treg[jj][2],
                         h3 = treg[jj][3], h4 = treg[jj][4];
                // k = dj*3+di multiplies x[r+di-1][c+dj-1]
                float a = hi_half_f32(h4);      // T9
                FMAMIX_LO(a, w00, h0);
                FMAMIX_HI(a, w10, h0);
                FMAMIX_LO(a, w20, h1);
                FMAMIX_HI(a, w01, h1);
                FMAMIX_LO(a, w11, h2);
                FMAMIX_HI(a, w21, h2);
                FMAMIX_LO(a, w02, h3);
                FMAMIX_HI(a, w12, h3);
                FMAMIX_LO(a, w22, h4);
                if ((s & 1) == 0) a = 1.0f / (1.0f + __expf(-a));

                int gi = ri + r;
                if (s < 6) {
                    bool rowok = (r <= WTR - 2);
                    bool inimg = ((unsigned)gi < (unsigned)Hd) && colin;
                    if (rowok) nxt[r * WLP + c] = inimg ? a : 0.0f;
                } else {
                    // Direct global store of the core (always in-image).
                    if (colcore && r >= WH && r <= WTR - 1 - WH)
                        ob[gi * Wd + gj] = a;
                }

                w00 = w10; w01 = w11; w02 = w12;
                w10 = w20; w11 = w21; w12 = w22;
            }
        }
        if (s < 6) {
            __syncthreads();
            float* tmp = cur; cur = nxt; nxt = tmp;
        }
    }
}

// ---------------------------------------------------------------------------
// Workspace: T only (B*5*H*W half2 = 40 MB).
// ---------------------------------------------------------------------------
extern "C" void kernel_launch(void* const* d_in, const int* in_sizes, int n_in,
                              void* d_out, int out_size, void* d_ws, size_t ws_size,
                              hipStream_t stream) {
    const float* x  = (const float*)d_in[0];
    const float* Wu = (const float*)d_in[1];
    const float* bu = (const float*)d_in[2];
    float* out = (float*)d_out;
    __half2* T = (__half2*)d_ws;

    conv_step0_kernel<<<8192, CTH2, 0, stream>>>(x, Wu, bu, T, out);

    for (int t = 1; t < Td; ++t)
        fused6_wide_kernel<<<256, WTHR, 0, stream>>>(out + (size_t)(t - 1) * HWc, T,
                                                     out + (size_t)t * HWc);
}